// Round 21
// baseline (264.691 us; speedup 1.0000x reference)
//
#include <hip/hip_runtime.h>
#include <math.h>

#define LDIM 2048
#define DDIM 128
#define BDIM 16
#define FDIM 100
// Split-K bf16 GEMM, dedup'd panels: A' = [AH | AL], B' = [BH | BL] (K=256 stored).
// Per 32-K chunk the 3 Markidis products are computed explicitly:
//   acc += AH.BH + AL.BH + AH.BL   (== fp32 ctx.main^T to ~1e-4)
// Panel layout per (batch,row-panel): [32 koct][128 row][8 elems] bf16.
#define PANEL_U16 (32 * 1024)
// conv-as-GEMM: K = 3*128 = 384, N = 112 (100 filters padded to 7 tiles of 16)
#define FPAD 112
#define CT 64            // t-rows per conv block
#define ACAP 64          // per-target attention contribution list capacity

typedef unsigned short u16;
typedef __bf16 bf16x8 __attribute__((ext_vector_type(8)));
typedef float f32x4 __attribute__((ext_vector_type(4)));

__device__ inline unsigned f2bfu(float x) {  // fp32 -> bf16 bits, RNE
  unsigned u = __float_as_uint(x);
  return (u + 0x7FFFu + ((u >> 16) & 1u)) >> 16;
}
__device__ inline unsigned pk2(float a, float b) {
  return f2bfu(a) | (f2bfu(b) << 16);
}
__device__ inline float bfhi(float x) {  // value of the bf16 hi part
  return __uint_as_float(f2bfu(x) << 16);
}

__device__ inline void glds16(const u16* g, u16* l) {
  __builtin_amdgcn_global_load_lds(
      (const __attribute__((address_space(1))) void*)g,
      (__attribute__((address_space(3))) void*)l, 16, 0, 0);
}

// Exact top-3 insert, med3-accelerated. Values (4 ops, exact fp32):
//   v0' = max(v0,w); v1' = med3(v0,v1,w); v2' = max(v2, min(v1,w))
// Indices: 3 exact fp32 compares + 5 selects. NO value approximation --
// R10/R15 proved index selection needs full fp32 resolution of W.
__device__ inline void ins3(float w, int idx, float v[3], int id[3]) {
  bool c0 = w > v[0], c1 = w > v[1], c2 = w > v[2];
  int n0 = c0 ? idx : id[0];
  int n1 = c0 ? id[0] : (c1 ? idx : id[1]);
  int n2 = c1 ? id[1] : (c2 ? idx : id[2]);
  id[0] = n0; id[1] = n1; id[2] = n2;
  float nv2 = fmaxf(v[2], fminf(v[1], w));       // min3(v0,v1,w) == min(v1,w) since v1<=v0
  float nv1 = __builtin_amdgcn_fmed3f(v[0], v[1], w);
  v[0] = fmaxf(v[0], w);
  v[1] = nv1; v[2] = nv2;
}

// Expand fp32 inputs into dedup'd split-bf16 panel layout (hi|lo), ctx and main.
__global__ __launch_bounds__(256) void split_convert(const float* __restrict__ ctx,
    const float* __restrict__ mn, u16* __restrict__ ctxS, u16* __restrict__ mnS) {
  const int b = blockIdx.y;
  const int rp = blockIdx.x & 15, og = blockIdx.x >> 4;  // og 0..7
  const int tid = threadIdx.x;
  const int row = tid & 127;
  const int o = og * 2 + (tid >> 7);                     // source k-octet 0..15
  const size_t srcOff = (((size_t)b * LDIM + rp * 128 + row) * DDIM + o * 8);
  const float4 c0 = *(const float4*)(ctx + srcOff);
  const float4 c1 = *(const float4*)(ctx + srcOff + 4);
  const float4 m0 = *(const float4*)(mn + srcOff);
  const float4 m1 = *(const float4*)(mn + srcOff + 4);
  uint4 chi = make_uint4(pk2(c0.x,c0.y), pk2(c0.z,c0.w), pk2(c1.x,c1.y), pk2(c1.z,c1.w));
  uint4 clo = make_uint4(pk2(c0.x-bfhi(c0.x), c0.y-bfhi(c0.y)),
                         pk2(c0.z-bfhi(c0.z), c0.w-bfhi(c0.w)),
                         pk2(c1.x-bfhi(c1.x), c1.y-bfhi(c1.y)),
                         pk2(c1.z-bfhi(c1.z), c1.w-bfhi(c1.w)));
  uint4 mhi = make_uint4(pk2(m0.x,m0.y), pk2(m0.z,m0.w), pk2(m1.x,m1.y), pk2(m1.z,m1.w));
  uint4 mlo = make_uint4(pk2(m0.x-bfhi(m0.x), m0.y-bfhi(m0.y)),
                         pk2(m0.z-bfhi(m0.z), m0.w-bfhi(m0.w)),
                         pk2(m1.x-bfhi(m1.x), m1.y-bfhi(m1.y)),
                         pk2(m1.z-bfhi(m1.z), m1.w-bfhi(m1.w)));
  u16* dA = ctxS + ((size_t)b * 16 + rp) * PANEL_U16;
  u16* dB = mnS  + ((size_t)b * 16 + rp) * PANEL_U16;
  const int base = o * 1024 + row * 8;
  *(uint4*)(dA + base)         = chi;   // koct o      : AH
  *(uint4*)(dA + base + 16384) = clo;   // koct o + 16 : AL
  *(uint4*)(dB + base)         = mhi;   // koct o      : BH
  *(uint4*)(dB + base + 16384) = mlo;   // koct o + 16 : BL
}

// W[b][c][m] = ctx.main^T via dedup'd split-bf16 MFMA. W is NEVER stored.
// Main loop: 4 chunks of 32-K; per chunk stage AH/AL/BH/BL (8KB each).
// MFMAs sequenced j-outer (aH/aL resident, bH/bL streamed) to cap fragment
// liveness at 40 VGPR. __launch_bounds__(256,4) caps regs at 128 -> 4 waves/SIMD.
// Epilogue (R12-proven): quadrants staged to 64x65 LDS, whole-wave serial walks.
__global__ __launch_bounds__(256, 4) void gemm_mfma(const u16* __restrict__ A,
    const u16* __restrict__ B, unsigned* __restrict__ rowP,
    unsigned* __restrict__ colP) {
  __shared__ __attribute__((aligned(16))) char ldsbuf[33280];
  u16* AsH = (u16*)ldsbuf;           // 8 KB (4 kocts)
  u16* AsL = AsH + 4096;             // 8 KB
  u16* BsH = AsH + 8192;             // 8 KB
  u16* BsL = AsH + 12288;            // 8 KB
  float* stg = (float*)ldsbuf;       // epilogue: 2 x 4160 floats (64x65 each)
  const int b = blockIdx.z;
  const int rp = blockIdx.y, mp = blockIdx.x;
  const int tid = threadIdx.x;
  const int w = tid >> 6, lane = tid & 63;
  const int lr = lane & 15, lg = lane >> 4;
  const int wr = w >> 1, wc = w & 1;
  const u16* srcA = A + ((size_t)b * 16 + rp) * PANEL_U16;
  const u16* srcB = B + ((size_t)b * 16 + mp) * PANEL_U16;
  f32x4 acc[4][4];
  const f32x4 zz = {0.f, 0.f, 0.f, 0.f};
  #pragma unroll
  for (int i = 0; i < 4; i++)
    #pragma unroll
    for (int j = 0; j < 4; j++) acc[i][j] = zz;

  for (int ch = 0; ch < 4; ch++) {       // 32-K chunk = kocts ch*4..ch*4+3
    if (ch) __syncthreads();
    const int co = ch * 4096;            // u16 offset of chunk in H half
    #pragma unroll
    for (int q = 0; q < 2; q++) {
      const int c = q * 256 + w * 64;    // chunk-of-16B index base for this wave
      glds16(srcA + co         + (size_t)(c + lane) * 8, AsH + c * 8);
      glds16(srcA + 16384 + co + (size_t)(c + lane) * 8, AsL + c * 8);
      glds16(srcB + co         + (size_t)(c + lane) * 8, BsH + c * 8);
      glds16(srcB + 16384 + co + (size_t)(c + lane) * 8, BsL + c * 8);
    }
    __syncthreads();
    const int ao = lg * 1024 + (wr * 64 + lr) * 8;
    const int bo = lg * 1024 + (wc * 64 + lr) * 8;
    bf16x8 aH[4], aL[4];
    #pragma unroll
    for (int i = 0; i < 4; i++) aH[i] = *(const bf16x8*)&AsH[ao + i * 128];
    #pragma unroll
    for (int i = 0; i < 4; i++) aL[i] = *(const bf16x8*)&AsL[ao + i * 128];
    #pragma unroll
    for (int j = 0; j < 4; j++) {
      bf16x8 bHj = *(const bf16x8*)&BsH[bo + j * 128];
      #pragma unroll
      for (int i = 0; i < 4; i++)
        acc[i][j] = __builtin_amdgcn_mfma_f32_16x16x32_bf16(aH[i], bHj, acc[i][j], 0, 0, 0);
      #pragma unroll
      for (int i = 0; i < 4; i++)
        acc[i][j] = __builtin_amdgcn_mfma_f32_16x16x32_bf16(aL[i], bHj, acc[i][j], 0, 0, 0);
      bf16x8 bLj = *(const bf16x8*)&BsL[bo + j * 128];
      #pragma unroll
      for (int i = 0; i < 4; i++)
        acc[i][j] = __builtin_amdgcn_mfma_f32_16x16x32_bf16(aH[i], bLj, acc[i][j], 0, 0, 0);
    }
  }

  // ---- fused stats epilogue. C/D layout (m89, verified by R1 W-store):
  //      local row = i*16 + lg*4 + r, local col = j*16 + lr (within 64x64 quadrant).
  for (int rnd = 0; rnd < 2; rnd++) {
    __syncthreads();                       // main-loop LDS (or prev round stg) dead
    if (wr == rnd) {
      float* st = stg + wc * 4160;
      #pragma unroll
      for (int i = 0; i < 4; i++)
        #pragma unroll
        for (int r = 0; r < 4; r++) {
          const int row = i * 16 + lg * 4 + r;
          #pragma unroll
          for (int j = 0; j < 4; j++)
            st[row * 65 + j * 16 + lr] = acc[i][j][r];
        }
    }
    __syncthreads();
    {
      const int buf = tid >> 7;            // which staging buffer (== wc)
      const int role = (tid >> 6) & 1;     // 0: col reduce, 1: row reduce
      const int l6 = tid & 63;
      const float* st = stg + buf * 4160;
      float v[3] = {-3e38f,-3e38f,-3e38f}; int id[3] = {-1,-1,-1};
      float sm = 0.f, s2 = 0.f;
      if (role == 0) {
        // column l6 of this quadrant, over its 64 rows
        #pragma unroll 8
        for (int r = 0; r < 64; r++) {
          float wv = st[r * 65 + l6];
          sm += wv; s2 = fmaf(wv, wv, s2);
          ins3(wv, rp*128 + rnd*64 + r, v, id);
        }
        size_t rec = (((size_t)b*32 + rp*2 + rnd)*LDIM + mp*128 + buf*64 + l6) * 8;
        uint4 lo = make_uint4(__float_as_uint(v[0]), __float_as_uint(v[1]),
                              __float_as_uint(v[2]), __float_as_uint(sm));
        uint4 hi = make_uint4(__float_as_uint(s2), (unsigned)id[0],
                              (unsigned)id[1], (unsigned)id[2]);
        *(uint4*)(colP + rec)     = lo;
        *(uint4*)(colP + rec + 4) = hi;
      } else {
        // row l6 of this quadrant, over its 64 cols
        #pragma unroll 8
        for (int c = 0; c < 64; c++) {
          float wv = st[l6 * 65 + c];
          sm += wv; s2 = fmaf(wv, wv, s2);
          ins3(wv, mp*128 + buf*64 + c, v, id);
        }
        size_t rec = (((size_t)b*32 + mp*2 + buf)*LDIM + rp*128 + rnd*64 + l6) * 8;
        uint4 lo = make_uint4(__float_as_uint(v[0]), __float_as_uint(v[1]),
                              __float_as_uint(v[2]), __float_as_uint(sm));
        uint4 hi = make_uint4(__float_as_uint(s2), (unsigned)id[0],
                              (unsigned)id[1], (unsigned)id[2]);
        *(uint4*)(rowP + rec)     = lo;
        *(uint4*)(rowP + rec + 4) = hi;
      }
    }
  }
}

// Merge 32 per-tile partials per index; z=0 -> row stats, z=1 -> col stats.
// z=0 additionally routes the top-3 scatter: one 4B atomic per (row, t) appends
// (c,t) to the target row's list (avg 3 entries/target). Overflow (>ACAP,
// ~never on random data) falls back to direct atomicAdd into zeroed attC.
__global__ __launch_bounds__(256) void stats_combine(const unsigned* __restrict__ rowP,
    const unsigned* __restrict__ colP,
    float* __restrict__ rw, int* __restrict__ ri, float* __restrict__ rs,
    float* __restrict__ cw, int* __restrict__ ci, float* __restrict__ cs,
    unsigned* __restrict__ cnt, unsigned* __restrict__ list,
    float* __restrict__ attC, const float* __restrict__ ctx) {
  const int b = blockIdx.y;
  const int c = blockIdx.x * 256 + threadIdx.x;
  const unsigned* P = blockIdx.z == 0 ? rowP : colP;
  float* w3 = blockIdx.z == 0 ? rw : cw;
  int*   i3 = blockIdx.z == 0 ? ri : ci;
  float* sd = blockIdx.z == 0 ? rs : cs;
  float v[3] = {-3e38f,-3e38f,-3e38f}; int id[3] = {-1,-1,-1};
  float sum = 0.f, sq = 0.f;
  for (int t = 0; t < 32; t++) {
    const unsigned* rec = P + (((size_t)b*32 + t)*LDIM + c) * 8;
    const uint4 lo = *(const uint4*)rec;
    const uint4 hi = *(const uint4*)(rec + 4);
    ins3(__uint_as_float(lo.x), (int)hi.y, v, id);
    ins3(__uint_as_float(lo.y), (int)hi.z, v, id);
    ins3(__uint_as_float(lo.z), (int)hi.w, v, id);
    sum += __uint_as_float(lo.w); sq += __uint_as_float(hi.x);
  }
  float inv = 1.f/(v[0]+v[1]+v[2]);
  size_t o = (size_t)b*LDIM + c;
  w3[o*3+0]=v[0]*inv; w3[o*3+1]=v[1]*inv; w3[o*3+2]=v[2]*inv;
  i3[o*3+0]=id[0]; i3[o*3+1]=id[1]; i3[o*3+2]=id[2];
  float mean = sum * (1.f/LDIM);
  float var = sq*(1.f/LDIM) - mean*mean;
  sd[o] = sqrtf(fmaxf(var, 0.f));
  if (blockIdx.z == 0) {
    #pragma unroll
    for (int t = 0; t < 3; t++) {
      int m = id[t];
      unsigned pos = atomicAdd(&cnt[(size_t)b*LDIM + m], 1u);
      if (pos < ACAP) {
        list[((size_t)b*LDIM + m)*ACAP + pos] = (unsigned)(c*4 + t);
      } else {
        float wv = v[t]*inv;
        for (int d = 0; d < DDIM; d++)
          atomicAdd(&attC[((size_t)b*LDIM + m)*DDIM + d],
                    wv * ctx[((size_t)b*LDIM + c)*DDIM + d]);
      }
    }
  }
}

// Convert conv weights to bf16 panel wB[ko 0..47][f 0..111][e 0..7]:
// wB[ko][f][e] = w[ks = ko/16][d = (ko%16)*8 + e][f], f >= FDIM -> 0.
__global__ __launch_bounds__(256) void conv_prep_w(const float* __restrict__ wv,
    u16* __restrict__ wB) {
  int idx = blockIdx.x * 256 + threadIdx.x;
  if (idx >= 48 * FPAD * 8) return;
  int e = idx & 7, f = (idx >> 3) % FPAD, ko = idx / (FPAD * 8);
  int ks = ko >> 4, d = ((ko & 15) << 3) | e;
  float val = (f < FDIM) ? wv[(ks * DDIM + d) * FDIM + f] : 0.f;
  wB[idx] = (u16)f2bfu(val);
}

// FUSED make_outputs + inline att-gather + conv1d(KS=3) + bias + relu + maxpool.
// The conv block computes its own 66 X-rows directly into the swizzled LDS tile:
//   z=0: X[t][d] = |ctx[t][d] - sum_k cw[t,k]*mn[ci[t,k]][d]| * rs[t]   (outputs_c)
//   z=1: X[t][d] = |mn[t][d] - attGather(t,d)| * cs[t]                  (outputs_m)
// attGather = sum over listed (c,tt): rw[c,tt]*ctx[c][d], plus attC base ONLY
// if the row overflowed (cnt > ACAP; ~never) -- no gather kernel, no attC
// round-trip in the common case. cnt/list loads are wave-uniform broadcasts.
__global__ __launch_bounds__(256) void conv_mfma(const float* __restrict__ ctx,
    const float* __restrict__ mn, const float* __restrict__ attC,
    const float* __restrict__ rs, const float* __restrict__ cw,
    const int* __restrict__ ci, const float* __restrict__ cs,
    const float* __restrict__ rw, const unsigned* __restrict__ cnt,
    const unsigned* __restrict__ list,
    const u16* __restrict__ wB, const float* __restrict__ bias,
    float* __restrict__ out) {
  const int b = blockIdx.y, z = blockIdx.z;
  const int t0 = blockIdx.x * CT;
  __shared__ u16 Xs[(CT + 2) * 128];   // rows of 256B, XOR-swizzled
  __shared__ float smax[FPAD];
  const int tid = threadIdx.x;
  for (int e = tid; e < (CT + 2) * 64; e += 256) {
    int row = e >> 6, p = e & 63;      // p = float2-pair index 0..63
    int t = t0 + row;
    int d2 = p * 2;
    float x0 = 0.f, x1 = 0.f;
    if (t < LDIM) {
      const size_t base = (size_t)b * LDIM + t;
      if (z == 0) {
        const float2 cx = *(const float2*)&ctx[base * DDIM + d2];
        float am0 = 0.f, am1 = 0.f;
        #pragma unroll
        for (int k = 0; k < 3; k++) {
          float wv = cw[base * 3 + k];
          const float2 g = *(const float2*)&mn[((size_t)b * LDIM + ci[base * 3 + k]) * DDIM + d2];
          am0 += wv * g.x; am1 += wv * g.y;
        }
        const float rsv = rs[base];
        x0 = fabsf(cx.x - am0) * rsv; x1 = fabsf(cx.y - am1) * rsv;
      } else {
        const float2 mm = *(const float2*)&mn[base * DDIM + d2];
        unsigned nr = cnt[base];
        float a0 = 0.f, a1 = 0.f;
        if (nr > ACAP) {                 // overflow backstop (~never taken)
          const float2 ac = *(const float2*)&attC[base * DDIM + d2];
          a0 = ac.x; a1 = ac.y;
        }
        unsigned n = nr > ACAP ? ACAP : nr;
        for (unsigned e2 = 0; e2 < n; e2++) {
          unsigned pk = list[base * ACAP + e2];
          int c = pk >> 2, tt = pk & 3;
          float wv = rw[((size_t)b * LDIM + c) * 3 + tt];
          const float2 g = *(const float2*)&ctx[((size_t)b * LDIM + c) * DDIM + d2];
          a0 += wv * g.x; a1 += wv * g.y;
        }
        const float csv = cs[base];
        x0 = fabsf(mm.x - a0) * csv; x1 = fabsf(mm.y - a1) * csv;
      }
    }
    int c16 = p >> 2, q4 = p & 3;
    int byte = row * 256 + ((c16 * 16) ^ ((row & 7) << 4)) + q4 * 4;
    *(unsigned*)((char*)Xs + byte) = pk2(x0, x1);
  }
  if (tid < FPAD) smax[tid] = 0.f;
  __syncthreads();
  const int w = tid >> 6, lane = tid & 63;
  const int lr = lane & 15, lg = lane >> 4;
  const int lt0 = w * 16;
  bf16x8 av[12];
  #pragma unroll
  for (int kk = 0; kk < 12; kk++) {
    int ko = kk * 4 + lg;          // k-octet 0..47; k = ko*8+e
    int ks = ko >> 4, d8 = ko & 15;
    int row = lt0 + lr + ks;
    int byte = row * 256 + ((d8 * 16) ^ ((row & 7) << 4));
    av[kk] = *(const bf16x8*)((const char*)Xs + byte);
  }
  for (int ft = 0; ft < 7; ft++) {
    f32x4 acc = {0.f, 0.f, 0.f, 0.f};
    #pragma unroll
    for (int kk = 0; kk < 12; kk++) {
      int ko = kk * 4 + lg;
      bf16x8 bv = *(const bf16x8*)&wB[((size_t)ko * FPAD + ft * 16 + lr) * 8];
      acc = __builtin_amdgcn_mfma_f32_16x16x32_bf16(av[kk], bv, acc, 0, 0, 0);
    }
    int f = ft * 16 + lr;
    float bb = (f < FDIM) ? bias[f] : 0.f;
    float mx = 0.f;
    #pragma unroll
    for (int r = 0; r < 4; r++) {
      int t = t0 + lt0 + lg * 4 + r;
      float y = fmaxf(acc[r] + bb, 0.f);
      if (t <= LDIM - 3) mx = fmaxf(mx, y);   // invalid t -> 0 (safe: relu-max >= 0)
    }
    mx = fmaxf(mx, __shfl_xor(mx, 16));
    mx = fmaxf(mx, __shfl_xor(mx, 32));
    if (lg == 0 && f < FDIM)
      atomicMax((unsigned*)&smax[f], __float_as_uint(mx));
  }
  __syncthreads();
  if (tid < FDIM)
    atomicMax((unsigned*)&out[(size_t)b * (2 * FDIM) + z * FDIM + tid],
              __float_as_uint(smax[tid]));
}

extern "C" void kernel_launch(void* const* d_in, const int* in_sizes, int n_in,
                              void* d_out, int out_size, void* d_ws, size_t ws_size,
                              hipStream_t stream) {
  const float* ctx   = (const float*)d_in[0];
  const float* mn    = (const float*)d_in[1];
  const float* wconv = (const float*)d_in[2];
  const float* bias  = (const float*)d_in[3];
  float* out = (float*)d_out;

  // pool accumulators must start at 0 (d_out is poisoned before every call)
  hipMemsetAsync(d_out, 0, sizeof(float)*(size_t)out_size, stream);

  // Workspace: [wB bf16 weight panel: 64K floats reserved] then per-iteration arrays.
  const size_t wbFloats = 65536;
  // Per-batch (floats/dwords) -- W, outC, outM, gathered-attC never round-tripped:
  //   row partial records:  32*L*8       = 524288
  //   col partial records:  32*L*8       = 524288
  //   final stats:          14*L         = 28672
  //   attC (overflow only): L*D          = 262144
  //   att lists:            L*(ACAP+1)   = 133120
  //   split-bf16 panels:    2*16*PANEL_U16/2 = 524288
  const size_t perBatchFloats = (size_t)32*LDIM*8 + (size_t)32*LDIM*8
                              + 14*(size_t)LDIM + (size_t)LDIM*DDIM
                              + (size_t)LDIM*(ACAP+1)
                              + 2*(size_t)16*PANEL_U16/2;
  const size_t perBatchBytes = perBatchFloats * sizeof(float);
  int nbMax = (int)((ws_size - wbFloats*sizeof(float)) / perBatchBytes);
  if (nbMax < 1) nbMax = 1;
  if (nbMax > BDIM) nbMax = BDIM;

  u16* wB = (u16*)d_ws;
  float* iterBase = (float*)d_ws + wbFloats;
  conv_prep_w<<<dim3((48*FPAD*8 + 255)/256), 256, 0, stream>>>(wconv, wB);

  for (int b0 = 0; b0 < BDIM; b0 += nbMax) {
    const int nb = (BDIM - b0 < nbMax) ? (BDIM - b0) : nbMax;
    unsigned* rowP = (unsigned*)iterBase;
    unsigned* colP = rowP + (size_t)nb*32*LDIM*8;
    float* rowW = (float*)(colP + (size_t)nb*32*LDIM*8);
    int*   rowI = (int*)(rowW + (size_t)nb*LDIM*3);
    float* rowS = (float*)(rowI + (size_t)nb*LDIM*3);
    float* colW = rowS + (size_t)nb*LDIM;
    int*   colI = (int*)(colW + (size_t)nb*LDIM*3);
    float* colS = (float*)(colI + (size_t)nb*LDIM*3);
    float* attC = colS + (size_t)nb*LDIM;
    unsigned* cntA = (unsigned*)(attC + (size_t)nb*LDIM*DDIM);
    unsigned* listA = cntA + (size_t)nb*LDIM;
    u16*   ctxS = (u16*)(listA + (size_t)nb*LDIM*ACAP);
    u16*   mnS  = ctxS + (size_t)nb*16*PANEL_U16;
    const float* ctxb = ctx + (size_t)b0*LDIM*DDIM;
    const float* mnb  = mn  + (size_t)b0*LDIM*DDIM;

    split_convert<<<dim3(128, nb), 256, 0, stream>>>(ctxb, mnb, ctxS, mnS);
    hipMemsetAsync(attC, 0, (size_t)nb*LDIM*DDIM*sizeof(float), stream);
    hipMemsetAsync(cntA, 0, (size_t)nb*LDIM*sizeof(unsigned), stream);
    gemm_mfma<<<dim3(LDIM/128, LDIM/128, nb), 256, 0, stream>>>(
        ctxS, mnS, rowP, colP);
    stats_combine<<<dim3(LDIM/256, nb, 2), 256, 0, stream>>>(
        rowP, colP, rowW, rowI, rowS, colW, colI, colS, cntA, listA, attC, ctxb);
    conv_mfma<<<dim3(LDIM/CT, nb, 2), 256, 0, stream>>>(
        ctxb, mnb, attC, rowS, colW, colI, colS, rowW, cntA, listA,
        wB, bias, out + (size_t)b0*2*FDIM);
  }
}

// Round 22
// 244.461 us; speedup vs baseline: 1.0828x; 1.0828x over previous
//
#include <hip/hip_runtime.h>
#include <math.h>

#define LDIM 2048
#define DDIM 128
#define BDIM 16
#define FDIM 100
// Split-K bf16 GEMM, dedup'd panels: A' = [AH | AL], B' = [BH | BL] (K=256 stored).
// Per 32-K chunk the 3 Markidis products are computed explicitly:
//   acc += AH.BH + AL.BH + AH.BL   (== fp32 ctx.main^T to ~1e-4)
// Panel layout per (batch,row-panel): [32 koct][128 row][8 elems] bf16.
#define PANEL_U16 (32 * 1024)
// conv-as-GEMM: K = 3*128 = 384, N = 112 (100 filters padded to 7 tiles of 16)
#define FPAD 112
#define CT 64            // t-rows per conv block
#define ACAP 64          // per-target attention contribution list capacity

typedef unsigned short u16;
typedef __bf16 bf16x8 __attribute__((ext_vector_type(8)));
typedef float f32x4 __attribute__((ext_vector_type(4)));

__device__ inline unsigned f2bfu(float x) {  // fp32 -> bf16 bits, RNE
  unsigned u = __float_as_uint(x);
  return (u + 0x7FFFu + ((u >> 16) & 1u)) >> 16;
}
__device__ inline unsigned pk2(float a, float b) {
  return f2bfu(a) | (f2bfu(b) << 16);
}
__device__ inline float bfhi(float x) {  // value of the bf16 hi part
  return __uint_as_float(f2bfu(x) << 16);
}

__device__ inline void glds16(const u16* g, u16* l) {
  __builtin_amdgcn_global_load_lds(
      (const __attribute__((address_space(1))) void*)g,
      (__attribute__((address_space(3))) void*)l, 16, 0, 0);
}

// Exact top-3 insert, med3-accelerated. Values (4 ops, exact fp32):
//   v0' = max(v0,w); v1' = med3(v0,v1,w); v2' = max(v2, min(v1,w))
// Indices: 3 exact fp32 compares + 5 selects. NO value approximation --
// R10/R15 proved index selection needs full fp32 resolution of W.
__device__ inline void ins3(float w, int idx, float v[3], int id[3]) {
  bool c0 = w > v[0], c1 = w > v[1], c2 = w > v[2];
  int n0 = c0 ? idx : id[0];
  int n1 = c0 ? id[0] : (c1 ? idx : id[1]);
  int n2 = c1 ? id[1] : (c2 ? idx : id[2]);
  id[0] = n0; id[1] = n1; id[2] = n2;
  float nv2 = fmaxf(v[2], fminf(v[1], w));       // min3(v0,v1,w) == min(v1,w) since v1<=v0
  float nv1 = __builtin_amdgcn_fmed3f(v[0], v[1], w);
  v[0] = fmaxf(v[0], w);
  v[1] = nv1; v[2] = nv2;
}

// Expand fp32 inputs into dedup'd split-bf16 panel layout (hi|lo), ctx and main.
__global__ __launch_bounds__(256) void split_convert(const float* __restrict__ ctx,
    const float* __restrict__ mn, u16* __restrict__ ctxS, u16* __restrict__ mnS) {
  const int b = blockIdx.y;
  const int rp = blockIdx.x & 15, og = blockIdx.x >> 4;  // og 0..7
  const int tid = threadIdx.x;
  const int row = tid & 127;
  const int o = og * 2 + (tid >> 7);                     // source k-octet 0..15
  const size_t srcOff = (((size_t)b * LDIM + rp * 128 + row) * DDIM + o * 8);
  const float4 c0 = *(const float4*)(ctx + srcOff);
  const float4 c1 = *(const float4*)(ctx + srcOff + 4);
  const float4 m0 = *(const float4*)(mn + srcOff);
  const float4 m1 = *(const float4*)(mn + srcOff + 4);
  uint4 chi = make_uint4(pk2(c0.x,c0.y), pk2(c0.z,c0.w), pk2(c1.x,c1.y), pk2(c1.z,c1.w));
  uint4 clo = make_uint4(pk2(c0.x-bfhi(c0.x), c0.y-bfhi(c0.y)),
                         pk2(c0.z-bfhi(c0.z), c0.w-bfhi(c0.w)),
                         pk2(c1.x-bfhi(c1.x), c1.y-bfhi(c1.y)),
                         pk2(c1.z-bfhi(c1.z), c1.w-bfhi(c1.w)));
  uint4 mhi = make_uint4(pk2(m0.x,m0.y), pk2(m0.z,m0.w), pk2(m1.x,m1.y), pk2(m1.z,m1.w));
  uint4 mlo = make_uint4(pk2(m0.x-bfhi(m0.x), m0.y-bfhi(m0.y)),
                         pk2(m0.z-bfhi(m0.z), m0.w-bfhi(m0.w)),
                         pk2(m1.x-bfhi(m1.x), m1.y-bfhi(m1.y)),
                         pk2(m1.z-bfhi(m1.z), m1.w-bfhi(m1.w)));
  u16* dA = ctxS + ((size_t)b * 16 + rp) * PANEL_U16;
  u16* dB = mnS  + ((size_t)b * 16 + rp) * PANEL_U16;
  const int base = o * 1024 + row * 8;
  *(uint4*)(dA + base)         = chi;   // koct o      : AH
  *(uint4*)(dA + base + 16384) = clo;   // koct o + 16 : AL
  *(uint4*)(dB + base)         = mhi;   // koct o      : BH
  *(uint4*)(dB + base + 16384) = mlo;   // koct o + 16 : BL
}

// W[b][c][m] = ctx.main^T via dedup'd split-bf16 MFMA. W is NEVER stored.
// Main loop: 4 chunks of 32-K; per chunk stage AH/AL/BH/BL (8KB each).
// MFMAs sequenced j-outer (aH/aL resident, bH/bL streamed) to cap fragment
// liveness at 40 VGPR. __launch_bounds__(256,4) caps regs at 128 -> 4 waves/SIMD.
// Epilogue (R12-proven): quadrants staged to 64x65 LDS, whole-wave serial walks.
__global__ __launch_bounds__(256, 4) void gemm_mfma(const u16* __restrict__ A,
    const u16* __restrict__ B, unsigned* __restrict__ rowP,
    unsigned* __restrict__ colP) {
  __shared__ __attribute__((aligned(16))) char ldsbuf[33280];
  u16* AsH = (u16*)ldsbuf;           // 8 KB (4 kocts)
  u16* AsL = AsH + 4096;             // 8 KB
  u16* BsH = AsH + 8192;             // 8 KB
  u16* BsL = AsH + 12288;            // 8 KB
  float* stg = (float*)ldsbuf;       // epilogue: 2 x 4160 floats (64x65 each)
  const int b = blockIdx.z;
  const int rp = blockIdx.y, mp = blockIdx.x;
  const int tid = threadIdx.x;
  const int w = tid >> 6, lane = tid & 63;
  const int lr = lane & 15, lg = lane >> 4;
  const int wr = w >> 1, wc = w & 1;
  const u16* srcA = A + ((size_t)b * 16 + rp) * PANEL_U16;
  const u16* srcB = B + ((size_t)b * 16 + mp) * PANEL_U16;
  f32x4 acc[4][4];
  const f32x4 zz = {0.f, 0.f, 0.f, 0.f};
  #pragma unroll
  for (int i = 0; i < 4; i++)
    #pragma unroll
    for (int j = 0; j < 4; j++) acc[i][j] = zz;

  for (int ch = 0; ch < 4; ch++) {       // 32-K chunk = kocts ch*4..ch*4+3
    if (ch) __syncthreads();
    const int co = ch * 4096;            // u16 offset of chunk in H half
    #pragma unroll
    for (int q = 0; q < 2; q++) {
      const int c = q * 256 + w * 64;    // chunk-of-16B index base for this wave
      glds16(srcA + co         + (size_t)(c + lane) * 8, AsH + c * 8);
      glds16(srcA + 16384 + co + (size_t)(c + lane) * 8, AsL + c * 8);
      glds16(srcB + co         + (size_t)(c + lane) * 8, BsH + c * 8);
      glds16(srcB + 16384 + co + (size_t)(c + lane) * 8, BsL + c * 8);
    }
    __syncthreads();
    const int ao = lg * 1024 + (wr * 64 + lr) * 8;
    const int bo = lg * 1024 + (wc * 64 + lr) * 8;
    bf16x8 aH[4], aL[4];
    #pragma unroll
    for (int i = 0; i < 4; i++) aH[i] = *(const bf16x8*)&AsH[ao + i * 128];
    #pragma unroll
    for (int i = 0; i < 4; i++) aL[i] = *(const bf16x8*)&AsL[ao + i * 128];
    #pragma unroll
    for (int j = 0; j < 4; j++) {
      bf16x8 bHj = *(const bf16x8*)&BsH[bo + j * 128];
      #pragma unroll
      for (int i = 0; i < 4; i++)
        acc[i][j] = __builtin_amdgcn_mfma_f32_16x16x32_bf16(aH[i], bHj, acc[i][j], 0, 0, 0);
      #pragma unroll
      for (int i = 0; i < 4; i++)
        acc[i][j] = __builtin_amdgcn_mfma_f32_16x16x32_bf16(aL[i], bHj, acc[i][j], 0, 0, 0);
      bf16x8 bLj = *(const bf16x8*)&BsL[bo + j * 128];
      #pragma unroll
      for (int i = 0; i < 4; i++)
        acc[i][j] = __builtin_amdgcn_mfma_f32_16x16x32_bf16(aH[i], bLj, acc[i][j], 0, 0, 0);
    }
  }

  // ---- fused stats epilogue. C/D layout (m89, verified by R1 W-store):
  //      local row = i*16 + lg*4 + r, local col = j*16 + lr (within 64x64 quadrant).
  for (int rnd = 0; rnd < 2; rnd++) {
    __syncthreads();                       // main-loop LDS (or prev round stg) dead
    if (wr == rnd) {
      float* st = stg + wc * 4160;
      #pragma unroll
      for (int i = 0; i < 4; i++)
        #pragma unroll
        for (int r = 0; r < 4; r++) {
          const int row = i * 16 + lg * 4 + r;
          #pragma unroll
          for (int j = 0; j < 4; j++)
            st[row * 65 + j * 16 + lr] = acc[i][j][r];
        }
    }
    __syncthreads();
    {
      const int buf = tid >> 7;            // which staging buffer (== wc)
      const int role = (tid >> 6) & 1;     // 0: col reduce, 1: row reduce
      const int l6 = tid & 63;
      const float* st = stg + buf * 4160;
      float v[3] = {-3e38f,-3e38f,-3e38f}; int id[3] = {-1,-1,-1};
      float sm = 0.f, s2 = 0.f;
      if (role == 0) {
        // column l6 of this quadrant, over its 64 rows
        #pragma unroll 8
        for (int r = 0; r < 64; r++) {
          float wv = st[r * 65 + l6];
          sm += wv; s2 = fmaf(wv, wv, s2);
          ins3(wv, rp*128 + rnd*64 + r, v, id);
        }
        size_t rec = (((size_t)b*32 + rp*2 + rnd)*LDIM + mp*128 + buf*64 + l6) * 8;
        uint4 lo = make_uint4(__float_as_uint(v[0]), __float_as_uint(v[1]),
                              __float_as_uint(v[2]), __float_as_uint(sm));
        uint4 hi = make_uint4(__float_as_uint(s2), (unsigned)id[0],
                              (unsigned)id[1], (unsigned)id[2]);
        *(uint4*)(colP + rec)     = lo;
        *(uint4*)(colP + rec + 4) = hi;
      } else {
        // row l6 of this quadrant, over its 64 cols
        #pragma unroll 8
        for (int c = 0; c < 64; c++) {
          float wv = st[l6 * 65 + c];
          sm += wv; s2 = fmaf(wv, wv, s2);
          ins3(wv, mp*128 + buf*64 + c, v, id);
        }
        size_t rec = (((size_t)b*32 + mp*2 + buf)*LDIM + rp*128 + rnd*64 + l6) * 8;
        uint4 lo = make_uint4(__float_as_uint(v[0]), __float_as_uint(v[1]),
                              __float_as_uint(v[2]), __float_as_uint(sm));
        uint4 hi = make_uint4(__float_as_uint(s2), (unsigned)id[0],
                              (unsigned)id[1], (unsigned)id[2]);
        *(uint4*)(rowP + rec)     = lo;
        *(uint4*)(rowP + rec + 4) = hi;
      }
    }
  }
}

// Merge 32 per-tile partials per index; z=0 -> row stats, z=1 -> col stats.
// z=0 additionally routes the top-3 scatter: one 4B atomic per (row, t) appends
// (c,t) to the target row's list (avg 3 entries/target). Overflow (>ACAP,
// ~never on random data) falls back to direct atomicAdd into zeroed attC.
__global__ __launch_bounds__(256) void stats_combine(const unsigned* __restrict__ rowP,
    const unsigned* __restrict__ colP,
    float* __restrict__ rw, int* __restrict__ ri, float* __restrict__ rs,
    float* __restrict__ cw, int* __restrict__ ci, float* __restrict__ cs,
    unsigned* __restrict__ cnt, unsigned* __restrict__ list,
    float* __restrict__ attC, const float* __restrict__ ctx) {
  const int b = blockIdx.y;
  const int c = blockIdx.x * 256 + threadIdx.x;
  const unsigned* P = blockIdx.z == 0 ? rowP : colP;
  float* w3 = blockIdx.z == 0 ? rw : cw;
  int*   i3 = blockIdx.z == 0 ? ri : ci;
  float* sd = blockIdx.z == 0 ? rs : cs;
  float v[3] = {-3e38f,-3e38f,-3e38f}; int id[3] = {-1,-1,-1};
  float sum = 0.f, sq = 0.f;
  for (int t = 0; t < 32; t++) {
    const unsigned* rec = P + (((size_t)b*32 + t)*LDIM + c) * 8;
    const uint4 lo = *(const uint4*)rec;
    const uint4 hi = *(const uint4*)(rec + 4);
    ins3(__uint_as_float(lo.x), (int)hi.y, v, id);
    ins3(__uint_as_float(lo.y), (int)hi.z, v, id);
    ins3(__uint_as_float(lo.z), (int)hi.w, v, id);
    sum += __uint_as_float(lo.w); sq += __uint_as_float(hi.x);
  }
  float inv = 1.f/(v[0]+v[1]+v[2]);
  size_t o = (size_t)b*LDIM + c;
  w3[o*3+0]=v[0]*inv; w3[o*3+1]=v[1]*inv; w3[o*3+2]=v[2]*inv;
  i3[o*3+0]=id[0]; i3[o*3+1]=id[1]; i3[o*3+2]=id[2];
  float mean = sum * (1.f/LDIM);
  float var = sq*(1.f/LDIM) - mean*mean;
  sd[o] = sqrtf(fmaxf(var, 0.f));
  if (blockIdx.z == 0) {
    #pragma unroll
    for (int t = 0; t < 3; t++) {
      int m = id[t];
      unsigned pos = atomicAdd(&cnt[(size_t)b*LDIM + m], 1u);
      if (pos < ACAP) {
        list[((size_t)b*LDIM + m)*ACAP + pos] = (unsigned)(c*4 + t);
      } else {
        float wv = v[t]*inv;
        for (int d = 0; d < DDIM; d++)
          atomicAdd(&attC[((size_t)b*LDIM + m)*DDIM + d],
                    wv * ctx[((size_t)b*LDIM + c)*DDIM + d]);
      }
    }
  }
}

// attC[m][d] = sum over listed (c,t): rw[c,t] * ctx[c][d]. No atomics
// (plain accumulate on top of the overflow-only initial value).
__global__ __launch_bounds__(128) void gather_att(const float* __restrict__ ctx,
    const float* __restrict__ rw, const unsigned* __restrict__ cnt,
    const unsigned* __restrict__ list, float* __restrict__ attC) {
  const int b = blockIdx.y, m = blockIdx.x, d = threadIdx.x;
  const size_t base = (size_t)b*LDIM + m;
  unsigned n = cnt[base];
  if (n > ACAP) n = ACAP;
  float acc = attC[base*DDIM + d];
  for (unsigned e = 0; e < n; e++) {
    unsigned pk = list[base*ACAP + e];
    int c = pk >> 2, t = pk & 3;
    acc += rw[((size_t)b*LDIM + c)*3 + t] * ctx[((size_t)b*LDIM + c)*DDIM + d];
  }
  attC[base*DDIM + d] = acc;
}

// Convert conv weights to bf16 panel wB[ko 0..47][f 0..111][e 0..7]:
// wB[ko][f][e] = w[ks = ko/16][d = (ko%16)*8 + e][f], f >= FDIM -> 0.
__global__ __launch_bounds__(256) void conv_prep_w(const float* __restrict__ wv,
    u16* __restrict__ wB) {
  int idx = blockIdx.x * 256 + threadIdx.x;
  if (idx >= 48 * FPAD * 8) return;
  int e = idx & 7, f = (idx >> 3) % FPAD, ko = idx / (FPAD * 8);
  int ks = ko >> 4, d = ((ko & 15) << 3) | e;
  float val = (f < FDIM) ? wv[(ks * DDIM + d) * FDIM + f] : 0.f;
  wB[idx] = (u16)f2bfu(val);
}

// FUSED make_outputs + conv1d(KS=3) + bias + relu + maxpool (MFMA GEMM).
// The conv block computes its own 66 X-rows directly into the swizzled LDS tile:
//   z=0: X[t][d] = |ctx[t][d] - sum_k cw[t,k]*mn[ci[t,k]][d]| * rs[t]   (outputs_c)
//   z=1: X[t][d] = |mn[t][d] - attC[t][d]| * cs[t]                      (outputs_m)
__global__ __launch_bounds__(256) void conv_mfma(const float* __restrict__ ctx,
    const float* __restrict__ mn, const float* __restrict__ attC,
    const float* __restrict__ rs, const float* __restrict__ cw,
    const int* __restrict__ ci, const float* __restrict__ cs,
    const u16* __restrict__ wB, const float* __restrict__ bias,
    float* __restrict__ out) {
  const int b = blockIdx.y, z = blockIdx.z;
  const int t0 = blockIdx.x * CT;
  __shared__ u16 Xs[(CT + 2) * 128];   // rows of 256B, XOR-swizzled
  __shared__ float smax[FPAD];
  const int tid = threadIdx.x;
  for (int e = tid; e < (CT + 2) * 64; e += 256) {
    int row = e >> 6, p = e & 63;      // p = float2-pair index 0..63
    int t = t0 + row;
    int d2 = p * 2;
    float x0 = 0.f, x1 = 0.f;
    if (t < LDIM) {
      const size_t base = (size_t)b * LDIM + t;
      if (z == 0) {
        const float2 cx = *(const float2*)&ctx[base * DDIM + d2];
        float am0 = 0.f, am1 = 0.f;
        #pragma unroll
        for (int k = 0; k < 3; k++) {
          float wv = cw[base * 3 + k];
          const float2 g = *(const float2*)&mn[((size_t)b * LDIM + ci[base * 3 + k]) * DDIM + d2];
          am0 += wv * g.x; am1 += wv * g.y;
        }
        const float rsv = rs[base];
        x0 = fabsf(cx.x - am0) * rsv; x1 = fabsf(cx.y - am1) * rsv;
      } else {
        const float2 mm = *(const float2*)&mn[base * DDIM + d2];
        const float2 ac = *(const float2*)&attC[base * DDIM + d2];
        const float csv = cs[base];
        x0 = fabsf(mm.x - ac.x) * csv; x1 = fabsf(mm.y - ac.y) * csv;
      }
    }
    int c16 = p >> 2, q4 = p & 3;
    int byte = row * 256 + ((c16 * 16) ^ ((row & 7) << 4)) + q4 * 4;
    *(unsigned*)((char*)Xs + byte) = pk2(x0, x1);
  }
  if (tid < FPAD) smax[tid] = 0.f;
  __syncthreads();
  const int w = tid >> 6, lane = tid & 63;
  const int lr = lane & 15, lg = lane >> 4;
  const int lt0 = w * 16;
  bf16x8 av[12];
  #pragma unroll
  for (int kk = 0; kk < 12; kk++) {
    int ko = kk * 4 + lg;          // k-octet 0..47; k = ko*8+e
    int ks = ko >> 4, d8 = ko & 15;
    int row = lt0 + lr + ks;
    int byte = row * 256 + ((d8 * 16) ^ ((row & 7) << 4));
    av[kk] = *(const bf16x8*)((const char*)Xs + byte);
  }
  for (int ft = 0; ft < 7; ft++) {
    f32x4 acc = {0.f, 0.f, 0.f, 0.f};
    #pragma unroll
    for (int kk = 0; kk < 12; kk++) {
      int ko = kk * 4 + lg;
      bf16x8 bv = *(const bf16x8*)&wB[((size_t)ko * FPAD + ft * 16 + lr) * 8];
      acc = __builtin_amdgcn_mfma_f32_16x16x32_bf16(av[kk], bv, acc, 0, 0, 0);
    }
    int f = ft * 16 + lr;
    float bb = (f < FDIM) ? bias[f] : 0.f;
    float mx = 0.f;
    #pragma unroll
    for (int r = 0; r < 4; r++) {
      int t = t0 + lt0 + lg * 4 + r;
      float y = fmaxf(acc[r] + bb, 0.f);
      if (t <= LDIM - 3) mx = fmaxf(mx, y);   // invalid t -> 0 (safe: relu-max >= 0)
    }
    mx = fmaxf(mx, __shfl_xor(mx, 16));
    mx = fmaxf(mx, __shfl_xor(mx, 32));
    if (lg == 0 && f < FDIM)
      atomicMax((unsigned*)&smax[f], __float_as_uint(mx));
  }
  __syncthreads();
  if (tid < FDIM)
    atomicMax((unsigned*)&out[(size_t)b * (2 * FDIM) + z * FDIM + tid],
              __float_as_uint(smax[tid]));
}

extern "C" void kernel_launch(void* const* d_in, const int* in_sizes, int n_in,
                              void* d_out, int out_size, void* d_ws, size_t ws_size,
                              hipStream_t stream) {
  const float* ctx   = (const float*)d_in[0];
  const float* mn    = (const float*)d_in[1];
  const float* wconv = (const float*)d_in[2];
  const float* bias  = (const float*)d_in[3];
  float* out = (float*)d_out;

  // pool accumulators must start at 0 (d_out is poisoned before every call)
  hipMemsetAsync(d_out, 0, sizeof(float)*(size_t)out_size, stream);

  // Workspace: [wB bf16 weight panel: 64K floats reserved] then per-iteration arrays.
  const size_t wbFloats = 65536;
  // Per-batch (floats/dwords) -- W, outC, outM never materialized:
  //   row partial records:  32*L*8       = 524288
  //   col partial records:  32*L*8       = 524288
  //   final stats:          14*L         = 28672
  //   attC:                 L*D          = 262144
  //   att lists:            L*(ACAP+1)   = 133120
  //   split-bf16 panels:    2*16*PANEL_U16/2 = 524288
  const size_t perBatchFloats = (size_t)32*LDIM*8 + (size_t)32*LDIM*8
                              + 14*(size_t)LDIM + (size_t)LDIM*DDIM
                              + (size_t)LDIM*(ACAP+1)
                              + 2*(size_t)16*PANEL_U16/2;
  const size_t perBatchBytes = perBatchFloats * sizeof(float);
  int nbMax = (int)((ws_size - wbFloats*sizeof(float)) / perBatchBytes);
  if (nbMax < 1) nbMax = 1;
  if (nbMax > BDIM) nbMax = BDIM;

  u16* wB = (u16*)d_ws;
  float* iterBase = (float*)d_ws + wbFloats;
  conv_prep_w<<<dim3((48*FPAD*8 + 255)/256), 256, 0, stream>>>(wconv, wB);

  for (int b0 = 0; b0 < BDIM; b0 += nbMax) {
    const int nb = (BDIM - b0 < nbMax) ? (BDIM - b0) : nbMax;
    unsigned* rowP = (unsigned*)iterBase;
    unsigned* colP = rowP + (size_t)nb*32*LDIM*8;
    float* rowW = (float*)(colP + (size_t)nb*32*LDIM*8);
    int*   rowI = (int*)(rowW + (size_t)nb*LDIM*3);
    float* rowS = (float*)(rowI + (size_t)nb*LDIM*3);
    float* colW = rowS + (size_t)nb*LDIM;
    int*   colI = (int*)(colW + (size_t)nb*LDIM*3);
    float* colS = (float*)(colI + (size_t)nb*LDIM*3);
    float* attC = colS + (size_t)nb*LDIM;
    unsigned* cntA = (unsigned*)(attC + (size_t)nb*LDIM*DDIM);
    unsigned* listA = cntA + (size_t)nb*LDIM;
    u16*   ctxS = (u16*)(listA + (size_t)nb*LDIM*ACAP);
    u16*   mnS  = ctxS + (size_t)nb*16*PANEL_U16;
    const float* ctxb = ctx + (size_t)b0*LDIM*DDIM;
    const float* mnb  = mn  + (size_t)b0*LDIM*DDIM;

    split_convert<<<dim3(128, nb), 256, 0, stream>>>(ctxb, mnb, ctxS, mnS);
    hipMemsetAsync(attC, 0, (size_t)nb*LDIM*DDIM*sizeof(float), stream);
    hipMemsetAsync(cntA, 0, (size_t)nb*LDIM*sizeof(unsigned), stream);
    gemm_mfma<<<dim3(LDIM/128, LDIM/128, nb), 256, 0, stream>>>(
        ctxS, mnS, rowP, colP);
    stats_combine<<<dim3(LDIM/256, nb, 2), 256, 0, stream>>>(
        rowP, colP, rowW, rowI, rowS, colW, colI, colS, cntA, listA, attC, ctxb);
    gather_att<<<dim3(LDIM, nb), 128, 0, stream>>>(ctxb, rowW, cntA, listA, attC);
    conv_mfma<<<dim3(LDIM/CT, nb, 2), 256, 0, stream>>>(
        ctxb, mnb, attC, rowS, colW, colI, colS, wB, bias, out + (size_t)b0*2*FDIM);
  }
}